// Round 6
// baseline (1304.715 us; speedup 1.0000x reference)
//
#include <hip/hip_runtime.h>
#include <hip/hip_bf16.h>

#define NUM_C 1024
#define EMB   512
#define HID   512
#define BATCH 64
#define SEQ   512

typedef short bf16x8 __attribute__((ext_vector_type(8)));
typedef float f32x4  __attribute__((ext_vector_type(4)));

__device__ __forceinline__ unsigned short f2bf(float x) {
    unsigned u = __float_as_uint(x);
    u += 0x7fffu + ((u >> 16) & 1u);
    return (unsigned short)(u >> 16);
}
__device__ __forceinline__ float uaf(unsigned u) { return __uint_as_float(u); }

// fast tanh: exact at +-inf, ~1e-7 rel err, no branches
__device__ __forceinline__ float ftanh(float x) {
    float e = __expf(2.f * x);
    return 1.f - 2.f / (e + 1.f);
}

// ---------------------------------------------------------------------------
__global__ __launch_bounds__(256) void f32_to_bf16(const float* __restrict__ src,
                                                   unsigned short* __restrict__ dst, int n) {
    int i = blockIdx.x * 256 + threadIdx.x;
    if (i < n) dst[i] = f2bf(src[i]);
}

// ---------------------------------------------------------------------------
// fp32 vector GEMM (NT) for emb_proj = emb @ Wx^T + Wx_b + Wh_b
// ---------------------------------------------------------------------------
__global__ __launch_bounds__(256)
void gemm_nt_f32(const float* __restrict__ A, const float* __restrict__ B,
                 float* __restrict__ C, int M, int N, int K,
                 const float* __restrict__ bias1, const float* __restrict__ bias2) {
    __shared__ float As[64][33];
    __shared__ float Bs[64][33];

    const int n0 = blockIdx.x * 64;
    const int m0 = blockIdx.y * 64;
    const int tid = threadIdx.x;
    const int tx = tid & 15;
    const int ty = tid >> 4;

    float acc[4][4] = {{0.f}};

    for (int k0 = 0; k0 < K; k0 += 32) {
        #pragma unroll
        for (int i = 0; i < 2; ++i) {
            int f   = tid * 2 + i;
            int row = f >> 3;
            int kf  = f & 7;
            float4 va = *(const float4*)&A[(size_t)(m0 + row) * K + k0 + kf * 4];
            float4 vb = *(const float4*)&B[(size_t)(n0 + row) * K + k0 + kf * 4];
            As[row][kf * 4 + 0] = va.x; As[row][kf * 4 + 1] = va.y;
            As[row][kf * 4 + 2] = va.z; As[row][kf * 4 + 3] = va.w;
            Bs[row][kf * 4 + 0] = vb.x; Bs[row][kf * 4 + 1] = vb.y;
            Bs[row][kf * 4 + 2] = vb.z; Bs[row][kf * 4 + 3] = vb.w;
        }
        __syncthreads();
        #pragma unroll
        for (int kk = 0; kk < 32; ++kk) {
            float a[4], b[4];
            #pragma unroll
            for (int i = 0; i < 4; ++i) a[i] = As[ty * 4 + i][kk];
            #pragma unroll
            for (int j = 0; j < 4; ++j) b[j] = Bs[tx * 4 + j][kk];
            #pragma unroll
            for (int i = 0; i < 4; ++i)
                #pragma unroll
                for (int j = 0; j < 4; ++j)
                    acc[i][j] += a[i] * b[j];
        }
        __syncthreads();
    }

    float bb[4];
    #pragma unroll
    for (int j = 0; j < 4; ++j) {
        int n = n0 + tx * 4 + j;
        bb[j] = bias1[n] + bias2[n];
    }
    #pragma unroll
    for (int i = 0; i < 4; ++i) {
        size_t m = (size_t)(m0 + ty * 4 + i);
        float4 ov;
        ov.x = acc[i][0] + bb[0]; ov.y = acc[i][1] + bb[1];
        ov.z = acc[i][2] + bb[2]; ov.w = acc[i][3] + bb[3];
        *(float4*)&C[m * N + n0 + tx * 4] = ov;
    }
}

// ---------------------------------------------------------------------------
// LTC scan v6: distributed finish + register-staged mac + 2 barriers/step.
// 8 slices x 64 rows, W f32 in regs, 2 batches/block, grid=256.
//   P1: macA(s)                      [all waves; h staged to regs]   BAR
//   P2: finishA(s)+storeA [rows spread 8/wave, shfl reduce] ; pollB(s-1)
//   P3: macB(s)                                                      BAR
//   P4: finishB(s)+storeB ; pollA(s)
// Wave w consumes only hfX[w*64..+63], which wave w itself polls (or, for
// w==sl, is written by the distributed finish) -> P2/P4 need no barrier.
// Exchange: sentinel-validated (0x7F7F) relaxed agent atomics, as before.
// ---------------------------------------------------------------------------
__global__ __launch_bounds__(512, 2)
void ltc_scan6(const int* __restrict__ q, const int* __restrict__ r,
               const float* __restrict__ emb_proj, const float* __restrict__ Wh,
               const float* __restrict__ tau, unsigned short* __restrict__ hs_bf) {
    __shared__ float hfA[512], hfB[512], psA[512], psB[512];
    __shared__ int idA[512], idB[512];

    const int tid  = threadIdx.x;
    const int sl   = blockIdx.x >> 5;     // slice: owns h rows sl*64..+63
    const int bp   = blockIdx.x & 31;
    const int bA   = bp * 2, bB = bA + 1;
    const int lane = tid & 63;
    const int w    = tid >> 6;            // wave = k-chunk = partner slice

    // W chunk -> regs: row sl*64+lane, cols w*64..+63 (fp32, 64 VGPR)
    float4 wr_[16];
    {
        const float* wrow = Wh + (size_t)(sl * 64 + lane) * 512 + w * 64;
        #pragma unroll
        for (int i = 0; i < 16; ++i) wr_[i] = ((const float4*)wrow)[i];
    }

    hfA[tid] = 0.f; hfB[tid] = 0.f;
    idA[tid] = q[bA * SEQ + tid] + NUM_C * r[bA * SEQ + tid];
    idB[tid] = q[bB * SEQ + tid] + NUM_C * r[bB * SEQ + tid];

    // finish duty: lanes 0-7 of wave w own global h rows sl*64 + w*8 + lane
    const int frow = sl * 64 + w * 8 + lane;      // valid for lane<8
    float rtau = 0.f, hA = 0.f, hB = 0.f, embA = 0.f, embB = 0.f;
    if (lane < 8) rtau = 1.0f / tau[frow];

    unsigned* hswA = (unsigned*)(hs_bf + (size_t)bA * SEQ * HID);
    unsigned* hswB = (unsigned*)(hs_bf + (size_t)bB * SEQ * HID);
    const float4* hA4 = (const float4*)(hfA + w * 64);
    const float4* hB4 = (const float4*)(hfB + w * 64);
    __syncthreads();

    if (lane < 8) {
        embA = emb_proj[(size_t)idA[0] * HID + frow];
        embB = emb_proj[(size_t)idB[0] * HID + frow];
    }

    for (int s = 0; s < SEQ; ++s) {
        // ---------------- P1: mac A (register-staged h) ----------------
        {
            float4 hb[16];
            #pragma unroll
            for (int i = 0; i < 16; ++i) hb[i] = hA4[i];
            float a0 = 0.f, a1 = 0.f, a2 = 0.f, a3 = 0.f;
            #pragma unroll
            for (int i = 0; i < 16; ++i) {
                a0 += wr_[i].x * hb[i].x; a1 += wr_[i].y * hb[i].y;
                a2 += wr_[i].z * hb[i].z; a3 += wr_[i].w * hb[i].w;
            }
            psA[w * 64 + lane] = (a0 + a1) + (a2 + a3);
        }
        __syncthreads();

        // ------- P2: finishA(s) [8 rows/wave] + storeA ; pollB(s-1) -------
        {
            float p = psA[(lane >> 3) * 64 + w * 8 + (lane & 7)];
            p += __shfl_xor(p, 8); p += __shfl_xor(p, 16); p += __shfl_xor(p, 32);
            unsigned us = 0;
            if (lane < 8) {
                float pre = embA + p;
                float hn = hA + (ftanh(pre) - hA) * rtau;
                hA = hn;
                hfA[frow] = hn;
                us = f2bf(hn);
            }
            unsigned ot = (unsigned)__shfl_xor((int)us, 1);
            if (lane < 8 && !(lane & 1))
                __hip_atomic_store(&hswA[s * 256 + sl * 32 + w * 4 + (lane >> 1)],
                                   us | (ot << 16), __ATOMIC_RELAXED,
                                   __HIP_MEMORY_SCOPE_AGENT);
            if (lane < 8 && s + 1 < SEQ)
                embA = emb_proj[(size_t)idA[s + 1] * HID + frow];

            if (w != sl && s > 0 && lane < 32) {
                unsigned* ap = &hswB[(s - 1) * 256 + w * 32 + lane];
                unsigned word = __hip_atomic_load(ap, __ATOMIC_RELAXED,
                                                  __HIP_MEMORY_SCOPE_AGENT);
                while ((word & 0xffffu) == 0x7f7fu) {
                    __builtin_amdgcn_s_sleep(1);
                    word = __hip_atomic_load(ap, __ATOMIC_RELAXED,
                                             __HIP_MEMORY_SCOPE_AGENT);
                }
                float2 hv; hv.x = uaf(word << 16); hv.y = uaf(word & 0xffff0000u);
                *(float2*)&hfB[w * 64 + 2 * lane] = hv;
            }
        }
        // (no barrier: each wave consumes only what it wrote/polled itself;
        //  cross-wave hf writes are fenced by the next mac barrier)

        // ---------------- P3: mac B (register-staged h) ----------------
        {
            float4 hb[16];
            #pragma unroll
            for (int i = 0; i < 16; ++i) hb[i] = hB4[i];
            float a0 = 0.f, a1 = 0.f, a2 = 0.f, a3 = 0.f;
            #pragma unroll
            for (int i = 0; i < 16; ++i) {
                a0 += wr_[i].x * hb[i].x; a1 += wr_[i].y * hb[i].y;
                a2 += wr_[i].z * hb[i].z; a3 += wr_[i].w * hb[i].w;
            }
            psB[w * 64 + lane] = (a0 + a1) + (a2 + a3);
        }
        __syncthreads();

        // ------- P4: finishB(s) [8 rows/wave] + storeB ; pollA(s) -------
        {
            float p = psB[(lane >> 3) * 64 + w * 8 + (lane & 7)];
            p += __shfl_xor(p, 8); p += __shfl_xor(p, 16); p += __shfl_xor(p, 32);
            unsigned us = 0;
            if (lane < 8) {
                float pre = embB + p;
                float hn = hB + (ftanh(pre) - hB) * rtau;
                hB = hn;
                hfB[frow] = hn;
                us = f2bf(hn);
            }
            unsigned ot = (unsigned)__shfl_xor((int)us, 1);
            if (lane < 8 && !(lane & 1))
                __hip_atomic_store(&hswB[s * 256 + sl * 32 + w * 4 + (lane >> 1)],
                                   us | (ot << 16), __ATOMIC_RELAXED,
                                   __HIP_MEMORY_SCOPE_AGENT);
            if (lane < 8 && s + 1 < SEQ)
                embB = emb_proj[(size_t)idB[s + 1] * HID + frow];

            if (w != sl && s + 1 < SEQ && lane < 32) {
                unsigned* ap = &hswA[s * 256 + w * 32 + lane];
                unsigned word = __hip_atomic_load(ap, __ATOMIC_RELAXED,
                                                  __HIP_MEMORY_SCOPE_AGENT);
                while ((word & 0xffffu) == 0x7f7fu) {
                    __builtin_amdgcn_s_sleep(1);
                    word = __hip_atomic_load(ap, __ATOMIC_RELAXED,
                                             __HIP_MEMORY_SCOPE_AGENT);
                }
                float2 hv; hv.x = uaf(word << 16); hv.y = uaf(word & 0xffff0000u);
                *(float2*)&hfA[w * 64 + 2 * lane] = hv;
            }
        }
        // (no barrier: same argument as after P2)
    }
}

// ---------------------------------------------------------------------------
// Output GEMM: y = sigmoid(hs_bf @ Wo_bf^T + Wo_b), bf16 MFMA 16x16x32.
// ---------------------------------------------------------------------------
__global__ __launch_bounds__(256)
void gemm_out_bf16(const unsigned short* __restrict__ A,   // [M][512]
                   const unsigned short* __restrict__ B,   // [1024][512]
                   const float* __restrict__ bias,
                   float* __restrict__ C, int M) {
    __shared__ __align__(16) unsigned short As[128 * 32];
    __shared__ __align__(16) unsigned short Bs[128 * 32];

    const int tid = threadIdx.x;
    const int n0 = blockIdx.x * 128;
    const int m0 = blockIdx.y * 128;
    const int w  = tid >> 6;
    const int l  = tid & 63;
    const int wr = w >> 1, wc = w & 1;
    const int lr = l & 15;
    const int lq = l >> 4;

    f32x4 acc[4][4];
    #pragma unroll
    for (int i = 0; i < 4; ++i)
        #pragma unroll
        for (int jn = 0; jn < 4; ++jn)
            acc[i][jn] = (f32x4){0.f, 0.f, 0.f, 0.f};

    for (int k0 = 0; k0 < 512; k0 += 32) {
        #pragma unroll
        for (int p = 0; p < 2; ++p) {
            int flat = p * 256 + tid;
            int row  = flat >> 2;
            int c4   = flat & 3;
            *(uint4*)&As[row * 32 + c4 * 8] =
                *(const uint4*)&A[(size_t)(m0 + row) * 512 + k0 + c4 * 8];
            *(uint4*)&Bs[row * 32 + c4 * 8] =
                *(const uint4*)&B[(size_t)(n0 + row) * 512 + k0 + c4 * 8];
        }
        __syncthreads();

        bf16x8 af[4], bf[4];
        #pragma unroll
        for (int mf = 0; mf < 4; ++mf)
            af[mf] = *(const bf16x8*)&As[(wr * 64 + mf * 16 + lr) * 32 + lq * 8];
        #pragma unroll
        for (int nf = 0; nf < 4; ++nf)
            bf[nf] = *(const bf16x8*)&Bs[(wc * 64 + nf * 16 + lr) * 32 + lq * 8];

        #pragma unroll
        for (int mf = 0; mf < 4; ++mf)
            #pragma unroll
            for (int nf = 0; nf < 4; ++nf)
                acc[mf][nf] = __builtin_amdgcn_mfma_f32_16x16x32_bf16(
                    af[mf], bf[nf], acc[mf][nf], 0, 0, 0);
        __syncthreads();
    }

    #pragma unroll
    for (int mf = 0; mf < 4; ++mf) {
        #pragma unroll
        for (int nf = 0; nf < 4; ++nf) {
            int col = n0 + wc * 64 + nf * 16 + lr;
            float bb = bias[col];
            #pragma unroll
            for (int reg = 0; reg < 4; ++reg) {
                int rowm = m0 + wr * 64 + mf * 16 + lq * 4 + reg;
                float v = acc[mf][nf][reg] + bb;
                C[(size_t)rowm * 1024 + col] = 1.0f / (1.0f + expf(-v));
            }
        }
    }
}

// ---------------------------------------------------------------------------
extern "C" void kernel_launch(void* const* d_in, const int* in_sizes, int n_in,
                              void* d_out, int out_size, void* d_ws, size_t ws_size,
                              hipStream_t stream) {
    const int*   q    = (const int*)d_in[0];
    const int*   r    = (const int*)d_in[1];
    const float* emb  = (const float*)d_in[2];
    const float* Wh_w = (const float*)d_in[3];
    const float* Wh_b = (const float*)d_in[4];
    const float* Wx_w = (const float*)d_in[5];
    const float* Wx_b = (const float*)d_in[6];
    const float* tau  = (const float*)d_in[7];
    const float* Wo_w = (const float*)d_in[8];
    const float* Wo_b = (const float*)d_in[9];
    float* out = (float*)d_out;

    char* ws = (char*)d_ws;
    float*          emb_proj = (float*)ws;                                        // 4 MiB
    unsigned short* Wobf     = (unsigned short*)(ws + (4u << 20));                // 1 MiB
    unsigned short* hs_bf    = (unsigned short*)(ws + (5u << 20));                // 32 MiB

    // sentinel-fill hs (0x7F7F halfwords unreachable for |h|<=1 bf16)
    hipMemsetAsync(hs_bf, 0x7F, (size_t)BATCH * SEQ * HID * 2, stream);

    // Wo -> bf16 for the MFMA output GEMM
    f32_to_bf16<<<(1024 * 512) / 256, 256, 0, stream>>>(Wo_w, Wobf, 1024 * 512);

    // emb_proj = emb @ Wx^T + Wx_b + Wh_b (2048 distinct interaction rows)
    gemm_nt_f32<<<dim3(512 / 64, 2048 / 64), 256, 0, stream>>>(
        emb, Wx_w, emb_proj, 2048, 512, 512, Wx_b, Wh_b);

    // recurrence: 256 blocks (8 slices x 32 batch-pairs), static 12KB LDS
    ltc_scan6<<<256, 512, 0, stream>>>(q, r, emb_proj, Wh_w, tau, hs_bf);

    // y = sigmoid(hs @ Wo^T + Wo_b) via bf16 MFMA
    gemm_out_bf16<<<dim3(1024 / 128, (BATCH * SEQ) / 128), 256, 0, stream>>>(
        hs_bf, Wobf, Wo_b, out, BATCH * SEQ);
}